// Round 2
// baseline (253.867 us; speedup 1.0000x reference)
//
#include <hip/hip_runtime.h>

// Double-sparse matvec: y = A @ (B @ x), ELL form.
// M=N=K=8192, NNZ=256 per row, BATCH=32, fp32 in/out.
//
// R12 = R11 (LDS-staged gather) + two changes:
//  1. Out-of-segment PROC lanes now read a UNIFORM per-s LDS address
//     (broadcast, near-free) instead of a random masked row. R11 issued all
//     256 gathers per thread at random addresses -> 4x necessary LDS traffic.
//  2. DIAGNOSTIC dispatch: full stage replicated x8 into dead workspace.
//     Both spmv stages hide below the 43us poison-fill cutoff in the top-5
//     table, so per-stage time is unobservable; the x8 replica (>=110us)
//     must appear, giving direct per-stage duration + VALUBusy + LDS
//     conflicts + FETCH_SIZE for THIS kernel. dur_us this round is
//     deliberately inflated; next round removes the diag.
//
// Lane layout (per row): lane = q*4 + s.
//   s in [0,4): batch octet -- 8 fp16 batch columns (16B) per lane
//   q in [0,16): owns nnz block j = q*16 .. q*16+15

#define NNZ     256
#define BATCH   32
#define ROWS    8192
#define SEGR    2048          // table rows per LDS segment
#define NSEG    4
#define RPB     32            // rows per block
#define THREADS 512

typedef int      vi4 __attribute__((ext_vector_type(4)));
typedef float    vf4 __attribute__((ext_vector_type(4)));
typedef _Float16 vh2 __attribute__((ext_vector_type(2)));
typedef _Float16 vh4 __attribute__((ext_vector_type(4)));
typedef _Float16 vh8 __attribute__((ext_vector_type(8)));

union V8 { vh8 h8; vh2 h2[4]; unsigned u[4]; };

// ---- Stage 0: fp32 -> fp16 convert of x ([ROWS][BATCH], 256K elems) ----
__global__ __launch_bounds__(256) void cvt_f32_f16(
    const float* __restrict__ src, _Float16* __restrict__ dst)
{
    const int i = blockIdx.x * 256 + threadIdx.x;   // 4 elems per thread
    const vf4 v = *(const vf4*)(src + i * 4);
    vh4 h;
    h.x = (_Float16)v.x; h.y = (_Float16)v.y;
    h.z = (_Float16)v.z; h.w = (_Float16)v.w;
    *(vh4*)(dst + i * 4) = h;
}

// fp32 -> fp16 broadcast-pair (both halves of a u32 hold the same fp16)
static __device__ __forceinline__ unsigned hpack(float f)
{
    const unsigned short u = __builtin_bit_cast(unsigned short, (_Float16)f);
    return ((unsigned)u << 16) | (unsigned)u;
}

// One nnz: branchless segment-membership.
//  in-segment : gather the row's 16B slice for this s, pk_fma with bcast val
//  out-of-seg : read UNIFORM addr soffb (LDS broadcast across the 16 q-lanes
//               sharing s -> conflict-free), fma with packed fp16 zero.
#define PROC(K, BB)                                                           \
    do {                                                                      \
        const int  k_  = (K);                                                 \
        const bool in_ = (((unsigned)k_ >> 11) == (unsigned)p);               \
        const int  ra_ = (((k_ & 2047) << 6) + soffb);                        \
        const int  ad_ = in_ ? ra_ : soffb;                                   \
        V8 xv_;                                                               \
        xv_.h8 = *(const vh8*)(lb + ad_);                                     \
        const unsigned sel_ = in_ ? (BB) : 0u;                                \
        const vh2 b2_ = __builtin_bit_cast(vh2, sel_);                        \
        acc[t].h2[0] += b2_ * xv_.h2[0];                                      \
        acc[t].h2[1] += b2_ * xv_.h2[1];                                      \
        acc[t].h2[2] += b2_ * xv_.h2[2];                                      \
        acc[t].h2[3] += b2_ * xv_.h2[3];                                      \
    } while (0)

template <bool OUT16, int ITERS>
__global__ __launch_bounds__(THREADS, 2) void ell_spmv_lds(
    const int*      __restrict__ idx,   // [ROWS, NNZ]
    const float*    __restrict__ vals,  // [ROWS, NNZ]
    const _Float16* __restrict__ src,   // [ROWS, BATCH] fp16 gather table
    _Float16*       __restrict__ dst16, // [ROWS, BATCH] fp16   (OUT16)
    float*          __restrict__ dst32) // [BATCH, ROWS] fp32   (!OUT16)
{
    __shared__ __attribute__((aligned(16))) _Float16 lds[SEGR * BATCH]; // 128KB

    const int tid   = threadIdx.x;
    const int wave  = tid >> 6;          // 0..7
    const int lane  = tid & 63;
    const int s     = lane & 3;          // batch octet id
    const int q     = lane >> 2;         // nnz block of 16
    const int soffb = s * 16;            // byte offset within a 64B table row
    const int rbase = blockIdx.x * RPB;

    // ---- prologue: my 4 rows' idx/vals into registers (held across segs) ----
    vi4      iv[4][4];
    unsigned hh[4][16];
    #pragma unroll
    for (int t = 0; t < 4; ++t) {
        const int r = rbase + wave * 4 + t;
        const vi4* i4 = (const vi4*)(idx  + (size_t)r * NNZ) + q * 4;
        const vf4* v4 = (const vf4*)(vals + (size_t)r * NNZ) + q * 4;
        vf4 vv[4];
        #pragma unroll
        for (int u = 0; u < 4; ++u) iv[t][u] = __builtin_nontemporal_load(i4 + u);
        #pragma unroll
        for (int u = 0; u < 4; ++u) vv[u]    = __builtin_nontemporal_load(v4 + u);
        #pragma unroll
        for (int u = 0; u < 4; ++u) {
            hh[t][4*u+0] = hpack(vv[u].x);
            hh[t][4*u+1] = hpack(vv[u].y);
            hh[t][4*u+2] = hpack(vv[u].z);
            hh[t][4*u+3] = hpack(vv[u].w);
        }
    }

    V8 acc[4];
    #pragma unroll
    for (int t = 0; t < 4; ++t) {
        acc[t].u[0] = 0; acc[t].u[1] = 0; acc[t].u[2] = 0; acc[t].u[3] = 0;
    }

    const char* lb = (const char*)lds;

    #pragma unroll 1
    for (int it = 0; it < ITERS; ++it) {
        // ---- 4 segment passes over the gather table ----
        #pragma unroll 1
        for (int p = 0; p < NSEG; ++p) {
            __syncthreads();   // previous segment fully consumed before overwrite
            // stage 128KB: 16 rounds x (512 threads x 16B); linear LDS layout,
            // wave-uniform base + lane*16 as global_load_lds requires.
            const char* gseg = (const char*)(src + (size_t)p * SEGR * BATCH);
            #pragma unroll
            for (int tch = 0; tch < 16; ++tch) {
                const int off = tch * 8192 + tid * 16;
                __builtin_amdgcn_global_load_lds(
                    (const __attribute__((address_space(1))) unsigned int*)(gseg + off),
                    (__attribute__((address_space(3))) unsigned int*)((char*)lds + off),
                    16, 0, 0);
            }
            __syncthreads();   // compiler drains vmcnt before s_barrier

            #pragma unroll
            for (int t = 0; t < 4; ++t) {
                #pragma unroll
                for (int u = 0; u < 4; ++u) {
                    PROC(iv[t][u].x, hh[t][4*u+0]);
                    PROC(iv[t][u].y, hh[t][4*u+1]);
                    PROC(iv[t][u].z, hh[t][4*u+2]);
                    PROC(iv[t][u].w, hh[t][4*u+3]);
                }
            }
        }
    }

    // ---- epilogue: widen, reduce across the 16 q-blocks, store ----
    float* tile = (float*)lds;                      // reused only when !OUT16
    if (!OUT16) __syncthreads();                    // table reads all done

    #pragma unroll
    for (int t = 0; t < 4; ++t) {
        float a32[8];
        #pragma unroll
        for (int j = 0; j < 8; ++j) a32[j] = (float)acc[t].h8[j];
        #pragma unroll
        for (int d = 4; d < 64; d <<= 1) {
            #pragma unroll
            for (int j = 0; j < 8; ++j) a32[j] += __shfl_xor(a32[j], d);
        }
        if (OUT16) {
            if (q == 0) {                           // lanes 0..3: 64B coalesced
                const int r = rbase + wave * 4 + t;
                vh8 h;
                #pragma unroll
                for (int j = 0; j < 8; ++j) h[j] = (_Float16)a32[j];
                *(vh8*)(dst16 + (size_t)r * BATCH + s * 8) = h;
            }
        } else {
            if (q == 0) {                           // [32][33] padded tile
                const int rl = wave * 4 + t;
                #pragma unroll
                for (int j = 0; j < 8; ++j) tile[rl * 33 + s * 8 + j] = a32[j];
            }
        }
    }

    if (!OUT16) {
        __syncthreads();
        // out[b*ROWS + rbase + rr]: each thread stores 2 consecutive rows
        const int e  = tid * 2;                     // 1024 elems total
        const int b  = e >> 5;                      // 0..31
        const int rr = e & 31;                      // even
        float2 v2;
        v2.x = tile[rr * 33 + b];
        v2.y = tile[(rr + 1) * 33 + b];
        *(float2*)(dst32 + (size_t)b * ROWS + rbase + rr) = v2;
    }
}

#undef PROC

extern "C" void kernel_launch(void* const* d_in, const int* in_sizes, int n_in,
                              void* d_out, int out_size, void* d_ws, size_t ws_size,
                              hipStream_t stream) {
    (void)in_sizes; (void)n_in; (void)out_size; (void)ws_size;
    // setup_inputs order: x, a_idx, a_vals, b_idx, b_vals
    const float* x      = (const float*)d_in[0];   // [N, BATCH]
    const int*   a_idx  = (const int*)  d_in[1];   // [M, NNZ]
    const float* a_vals = (const float*)d_in[2];   // [M, NNZ]
    const int*   b_idx  = (const int*)  d_in[3];   // [K, NNZ]
    const float* b_vals = (const float*)d_in[4];   // [K, NNZ]
    float*       out    = (float*)d_out;           // [BATCH, M] fp32

    _Float16* bx16 = (_Float16*)d_ws;                        // 512 KB
    _Float16* x16  = (_Float16*)d_ws + (size_t)ROWS * BATCH; // 512 KB
    _Float16* diag = (_Float16*)d_ws + (size_t)2 * ROWS * BATCH; // dead scratch

    // Stage 0: convert x to fp16 (262144 elems, 4/thread)
    cvt_f32_f16<<<dim3(ROWS * BATCH / 4 / 256), dim3(256), 0, stream>>>(x, x16);
    // Stage 1: bx16 = B @ x
    ell_spmv_lds<true, 1><<<dim3(ROWS / RPB), dim3(THREADS), 0, stream>>>(
        b_idx, b_vals, x16, bx16, nullptr);
    // Stage 2: out = A @ bx (transposed store)
    ell_spmv_lds<false, 1><<<dim3(ROWS / RPB), dim3(THREADS), 0, stream>>>(
        a_idx, a_vals, bx16, nullptr, out);
    // DIAGNOSTIC: stage-1 pattern x8 into dead workspace -> must appear in
    // top-5 (>= ~110us), exposing per-stage duration + counters directly.
    ell_spmv_lds<true, 8><<<dim3(ROWS / RPB), dim3(THREADS), 0, stream>>>(
        b_idx, b_vals, x16, diag, nullptr);
}

// Round 3
// 184.756 us; speedup vs baseline: 1.3741x; 1.3741x over previous
//
#include <hip/hip_runtime.h>

// Double-sparse matvec: y = A @ (B @ x), ELL form.
// M=N=K=8192, NNZ=256 per row, BATCH=32, fp32 in/out.
//
// R13: FUSED single dispatch. R12's diag proved the 4-segment LDS pass runs
// 17.6us warm, but real stages ran ~34us: dispatch boundaries WB-INV L2
// (cross-XCD visibility), and the harness's 256MB ws-poison fill (43us,
// inside the timed region -- fits R10/R11/R12 totals to <0.5us) leaves
// L2/L3 dirty, so every dispatch re-pays a serialized cold idx/vals stream.
// Fix: fuse cvt + stage1 + stage2 into ONE kernel with 2 manual grid
// barriers. b-rows load overlaps the convert; a-rows load into REGISTERS
// during stage-B epilogue (registers survive barriers -> stage C does zero
// idx/vals memory traffic). Barrier counter lives in ws, zeroed by a tiny
// init dispatch (ws is poisoned each iteration).
//
// Grid: 256 blocks x 512 threads, 128KB LDS -> exactly 1 block/CU on 256
// CUs -> co-residency guaranteed; monotone barrier targets 256 then 512.
//
// Lane layout (per row): lane = q*4 + s.
//   s in [0,4): batch octet -- 8 fp16 batch columns (16B) per lane
//   q in [0,16): owns nnz block j = q*16 .. q*16+15

#define NNZ     256
#define BATCH   32
#define ROWS    8192
#define SEGR    2048          // table rows per LDS segment
#define NSEG    4
#define RPB     32            // rows per block
#define THREADS 512
#define BLOCKS  (ROWS / RPB)  // 256

typedef int      vi4 __attribute__((ext_vector_type(4)));
typedef float    vf4 __attribute__((ext_vector_type(4)));
typedef _Float16 vh2 __attribute__((ext_vector_type(2)));
typedef _Float16 vh8 __attribute__((ext_vector_type(8)));

union V8 { vh8 h8; vh2 h2[4]; unsigned u[4]; };

struct RowRegs { vi4 iv[4][4]; unsigned hh[4][16]; };

// fp32 -> fp16 broadcast-pair (both halves of a u32 hold the same fp16)
static __device__ __forceinline__ unsigned hpack(float f)
{
    const unsigned short u = __builtin_bit_cast(unsigned short, (_Float16)f);
    return ((unsigned)u << 16) | (unsigned)u;
}

// Load 4 rows' worth of idx/vals (this lane's q-block) into registers.
static __device__ __forceinline__ void load_rows(
    const int* __restrict__ idx, const float* __restrict__ vals,
    int r0, int q, RowRegs& R)
{
    #pragma unroll
    for (int t = 0; t < 4; ++t) {
        const vi4* i4 = (const vi4*)(idx  + (size_t)(r0 + t) * NNZ) + q * 4;
        const vf4* v4 = (const vf4*)(vals + (size_t)(r0 + t) * NNZ) + q * 4;
        vf4 vv[4];
        #pragma unroll
        for (int u = 0; u < 4; ++u) R.iv[t][u] = __builtin_nontemporal_load(i4 + u);
        #pragma unroll
        for (int u = 0; u < 4; ++u) vv[u]      = __builtin_nontemporal_load(v4 + u);
        #pragma unroll
        for (int u = 0; u < 4; ++u) {
            R.hh[t][4*u+0] = hpack(vv[u].x);
            R.hh[t][4*u+1] = hpack(vv[u].y);
            R.hh[t][4*u+2] = hpack(vv[u].z);
            R.hh[t][4*u+3] = hpack(vv[u].w);
        }
    }
}

// One nnz, branchless segment-membership:
//  in-segment : gather the row's 16B slice for this s, pk_fma with bcast val
//  out-of-seg : uniform addr soffb (LDS broadcast, conflict-free), fma by 0.
static __device__ __forceinline__ void proc1(
    int k, unsigned bb, int p, const char* lb, int soffb, V8& a)
{
    const bool in = (((unsigned)k >> 11) == (unsigned)p);
    const int  ra = ((k & 2047) << 6) + soffb;
    const int  ad = in ? ra : soffb;
    V8 xv;
    xv.h8 = *(const vh8*)(lb + ad);
    const vh2 b2 = __builtin_bit_cast(vh2, in ? bb : 0u);
    a.h2[0] += b2 * xv.h2[0];
    a.h2[1] += b2 * xv.h2[1];
    a.h2[2] += b2 * xv.h2[2];
    a.h2[3] += b2 * xv.h2[3];
}

// 4 segment passes over a [ROWS][BATCH] fp16 table staged through LDS.
static __device__ __forceinline__ void pass4(
    const RowRegs& R, const _Float16* __restrict__ src,
    _Float16* lds, int tid, int soffb, V8 acc[4])
{
    const char* lb = (const char*)lds;
    #pragma unroll 1
    for (int p = 0; p < NSEG; ++p) {
        __syncthreads();   // previous segment fully consumed before overwrite
        const char* gseg = (const char*)(src + (size_t)p * SEGR * BATCH);
        #pragma unroll
        for (int tch = 0; tch < 16; ++tch) {
            const int off = tch * 8192 + tid * 16;
            __builtin_amdgcn_global_load_lds(
                (const __attribute__((address_space(1))) unsigned int*)(gseg + off),
                (__attribute__((address_space(3))) unsigned int*)((char*)lds + off),
                16, 0, 0);
        }
        __syncthreads();   // compiler drains vmcnt before s_barrier

        #pragma unroll
        for (int t = 0; t < 4; ++t) {
            #pragma unroll
            for (int u = 0; u < 4; ++u) {
                proc1(R.iv[t][u].x, R.hh[t][4*u+0], p, lb, soffb, acc[t]);
                proc1(R.iv[t][u].y, R.hh[t][4*u+1], p, lb, soffb, acc[t]);
                proc1(R.iv[t][u].z, R.hh[t][4*u+2], p, lb, soffb, acc[t]);
                proc1(R.iv[t][u].w, R.hh[t][4*u+3], p, lb, soffb, acc[t]);
            }
        }
    }
}

// Manual grid barrier: monotone counter in ws (zeroed by bar_init dispatch).
// tid0 does release (threadfence -> buffer_wbl2) + arrive + acquire spin.
// All 256 blocks are co-resident by construction (1 block/CU, 256 CUs).
static __device__ __forceinline__ void gridbar(unsigned* bar, unsigned target)
{
    __syncthreads();                       // all block stores complete (vmcnt 0)
    if (threadIdx.x == 0) {
        __threadfence();                   // flush dirty L2 to L3 (release)
        __hip_atomic_fetch_add(bar, 1u, __ATOMIC_ACQ_REL, __HIP_MEMORY_SCOPE_AGENT);
        while (__hip_atomic_load(bar, __ATOMIC_ACQUIRE, __HIP_MEMORY_SCOPE_AGENT)
               < target) {
            __builtin_amdgcn_s_sleep(8);
        }
        __threadfence();                   // invalidate stale L1/L2 (acquire)
    }
    __syncthreads();
}

__global__ void bar_init(unsigned* bar)
{
    if (threadIdx.x == 0)
        __hip_atomic_store(bar, 0u, __ATOMIC_RELEASE, __HIP_MEMORY_SCOPE_AGENT);
}

__global__ __launch_bounds__(THREADS, 2) void fused_spmv(
    const float* __restrict__ x,       // [ROWS, BATCH] fp32
    const int*   __restrict__ a_idx,   // [ROWS, NNZ]
    const float* __restrict__ a_vals,  // [ROWS, NNZ]
    const int*   __restrict__ b_idx,   // [ROWS, NNZ]
    const float* __restrict__ b_vals,  // [ROWS, NNZ]
    _Float16*    __restrict__ x16,     // ws: [ROWS, BATCH] fp16
    _Float16*    __restrict__ bx16,    // ws: [ROWS, BATCH] fp16
    float*       __restrict__ out,     // [BATCH, ROWS] fp32
    unsigned*    __restrict__ bar)     // ws: grid barrier counter
{
    __shared__ __attribute__((aligned(16))) _Float16 lds[SEGR * BATCH]; // 128KB

    const int tid   = threadIdx.x;
    const int wave  = tid >> 6;          // 0..7
    const int lane  = tid & 63;
    const int s     = lane & 3;          // batch octet id
    const int q     = lane >> 2;         // nnz block of 16
    const int soffb = s * 16;            // byte offset within a 64B table row
    const int rbase = blockIdx.x * RPB;
    const int r0    = rbase + wave * 4;  // this wave's first row

    // ---- Phase A: b-rows prologue (cold HBM, issue first) + x convert ----
    RowRegs RB;
    load_rows(b_idx, b_vals, r0, q, RB);
    {
        const int gid = blockIdx.x * THREADS + tid;     // 2 f32 per thread
        const float2 v = ((const float2*)x)[gid];
        vh2 h; h.x = (_Float16)v.x; h.y = (_Float16)v.y;
        ((vh2*)x16)[gid] = h;
    }
    gridbar(bar, BLOCKS);                // x16 fully written, device-visible

    // ---- Phase B: bx = B @ x16 ----
    V8 acc[4];
    #pragma unroll
    for (int t = 0; t < 4; ++t) {
        acc[t].u[0] = 0; acc[t].u[1] = 0; acc[t].u[2] = 0; acc[t].u[3] = 0;
    }
    pass4(RB, x16, lds, tid, soffb, acc);

    // a-rows prologue NOW: latency hides under B-epilogue + barrier + C
    // staging; registers survive the grid barrier -> phase C needs zero
    // idx/vals memory traffic.
    RowRegs RA;
    load_rows(a_idx, a_vals, r0, q, RA);

    // B epilogue: widen, reduce across 16 q-blocks, write bx16 rows
    #pragma unroll
    for (int t = 0; t < 4; ++t) {
        float a32[8];
        #pragma unroll
        for (int j = 0; j < 8; ++j) a32[j] = (float)acc[t].h8[j];
        #pragma unroll
        for (int d = 4; d < 64; d <<= 1) {
            #pragma unroll
            for (int j = 0; j < 8; ++j) a32[j] += __shfl_xor(a32[j], d);
        }
        if (q == 0) {                    // lanes 0..3: 64B coalesced
            vh8 h;
            #pragma unroll
            for (int j = 0; j < 8; ++j) h[j] = (_Float16)a32[j];
            *(vh8*)(bx16 + (size_t)(r0 + t) * BATCH + s * 8) = h;
        }
    }
    gridbar(bar, 2 * BLOCKS);            // bx16 fully written, device-visible

    // ---- Phase C: out = A @ bx16 ----
    #pragma unroll
    for (int t = 0; t < 4; ++t) {
        acc[t].u[0] = 0; acc[t].u[1] = 0; acc[t].u[2] = 0; acc[t].u[3] = 0;
    }
    pass4(RA, bx16, lds, tid, soffb, acc);

    __syncthreads();                     // table reads done; reuse lds as tile
    float* tile = (float*)lds;           // [32][33] padded
    #pragma unroll
    for (int t = 0; t < 4; ++t) {
        float a32[8];
        #pragma unroll
        for (int j = 0; j < 8; ++j) a32[j] = (float)acc[t].h8[j];
        #pragma unroll
        for (int d = 4; d < 64; d <<= 1) {
            #pragma unroll
            for (int j = 0; j < 8; ++j) a32[j] += __shfl_xor(a32[j], d);
        }
        if (q == 0) {
            const int rl = wave * 4 + t;
            #pragma unroll
            for (int j = 0; j < 8; ++j) tile[rl * 33 + s * 8 + j] = a32[j];
        }
    }
    __syncthreads();
    // out[b*ROWS + rbase + rr]: each thread stores 2 consecutive rows
    {
        const int e  = tid * 2;          // 1024 elems total
        const int b  = e >> 5;           // 0..31
        const int rr = e & 31;           // even
        float2 v2;
        v2.x = tile[rr * 33 + b];
        v2.y = tile[(rr + 1) * 33 + b];
        *(float2*)(out + (size_t)b * ROWS + rbase + rr) = v2;
    }
}

extern "C" void kernel_launch(void* const* d_in, const int* in_sizes, int n_in,
                              void* d_out, int out_size, void* d_ws, size_t ws_size,
                              hipStream_t stream) {
    (void)in_sizes; (void)n_in; (void)out_size; (void)ws_size;
    // setup_inputs order: x, a_idx, a_vals, b_idx, b_vals
    const float* x      = (const float*)d_in[0];   // [N, BATCH]
    const int*   a_idx  = (const int*)  d_in[1];   // [M, NNZ]
    const float* a_vals = (const float*)d_in[2];   // [M, NNZ]
    const int*   b_idx  = (const int*)  d_in[3];   // [K, NNZ]
    const float* b_vals = (const float*)d_in[4];   // [K, NNZ]
    float*       out    = (float*)d_out;           // [BATCH, M] fp32

    _Float16* bx16 = (_Float16*)d_ws;                         // 512 KB
    _Float16* x16  = bx16 + (size_t)ROWS * BATCH;             // 512 KB
    unsigned* bar  = (unsigned*)((char*)d_ws +
                                 (size_t)2 * ROWS * BATCH * sizeof(_Float16));

    bar_init<<<dim3(1), dim3(64), 0, stream>>>(bar);
    fused_spmv<<<dim3(BLOCKS), dim3(THREADS), 0, stream>>>(
        x, a_idx, a_vals, b_idx, b_vals, x16, bx16, out, bar);
}

// Round 4
// 168.029 us; speedup vs baseline: 1.5109x; 1.0995x over previous
//
#include <hip/hip_runtime.h>

// Double-sparse matvec: y = A @ (B @ x), ELL form.
// M=N=K=8192, NNZ=256 per row, BATCH=32, fp32 in/out.
//
// R14 = R13 (fused single dispatch) + ONE change: relaxed-poll grid barrier.
// R13's barrier spun on __hip_atomic_load(ACQUIRE, AGENT): on gfx950 every
// agent-scope acquire emits a whole-XCD L2 `buffer_inv`, so up to 31 waiting
// CUs per XCD invalidated the shared L2 every ~0.2us while stragglers were
// still streaming idx/vals -> everything devolved to far-memory latency
// (VALUBusy 48%->15%, fused 124us vs ~45us sum-of-parts). Now: release fence
// ONCE before a RELAXED arrival RMW, RELAXED polls (coherent: agent scope
// makes the access bypass L2; no cache-maintenance side effects), acquire
// fence ONCE after the spin exits. Same ordering guarantees (C++
// fence-atomics pattern); R13's passing visibility structure unchanged.
//
// Grid: 256 blocks x 512 threads, 128KB LDS -> exactly 1 block/CU on 256
// CUs -> co-residency guaranteed; monotone barrier targets 256 then 512.
//
// Lane layout (per row): lane = q*4 + s.
//   s in [0,4): batch octet -- 8 fp16 batch columns (16B) per lane
//   q in [0,16): owns nnz block j = q*16 .. q*16+15

#define NNZ     256
#define BATCH   32
#define ROWS    8192
#define SEGR    2048          // table rows per LDS segment
#define NSEG    4
#define RPB     32            // rows per block
#define THREADS 512
#define BLOCKS  (ROWS / RPB)  // 256

typedef int      vi4 __attribute__((ext_vector_type(4)));
typedef float    vf4 __attribute__((ext_vector_type(4)));
typedef _Float16 vh2 __attribute__((ext_vector_type(2)));
typedef _Float16 vh8 __attribute__((ext_vector_type(8)));

union V8 { vh8 h8; vh2 h2[4]; unsigned u[4]; };

struct RowRegs { vi4 iv[4][4]; unsigned hh[4][16]; };

// fp32 -> fp16 broadcast-pair (both halves of a u32 hold the same fp16)
static __device__ __forceinline__ unsigned hpack(float f)
{
    const unsigned short u = __builtin_bit_cast(unsigned short, (_Float16)f);
    return ((unsigned)u << 16) | (unsigned)u;
}

// Load 4 rows' worth of idx/vals (this lane's q-block) into registers.
static __device__ __forceinline__ void load_rows(
    const int* __restrict__ idx, const float* __restrict__ vals,
    int r0, int q, RowRegs& R)
{
    #pragma unroll
    for (int t = 0; t < 4; ++t) {
        const vi4* i4 = (const vi4*)(idx  + (size_t)(r0 + t) * NNZ) + q * 4;
        const vf4* v4 = (const vf4*)(vals + (size_t)(r0 + t) * NNZ) + q * 4;
        vf4 vv[4];
        #pragma unroll
        for (int u = 0; u < 4; ++u) R.iv[t][u] = __builtin_nontemporal_load(i4 + u);
        #pragma unroll
        for (int u = 0; u < 4; ++u) vv[u]      = __builtin_nontemporal_load(v4 + u);
        #pragma unroll
        for (int u = 0; u < 4; ++u) {
            R.hh[t][4*u+0] = hpack(vv[u].x);
            R.hh[t][4*u+1] = hpack(vv[u].y);
            R.hh[t][4*u+2] = hpack(vv[u].z);
            R.hh[t][4*u+3] = hpack(vv[u].w);
        }
    }
}

// One nnz, branchless segment-membership:
//  in-segment : gather the row's 16B slice for this s, pk_fma with bcast val
//  out-of-seg : uniform addr soffb (LDS broadcast, conflict-free), fma by 0.
static __device__ __forceinline__ void proc1(
    int k, unsigned bb, int p, const char* lb, int soffb, V8& a)
{
    const bool in = (((unsigned)k >> 11) == (unsigned)p);
    const int  ra = ((k & 2047) << 6) + soffb;
    const int  ad = in ? ra : soffb;
    V8 xv;
    xv.h8 = *(const vh8*)(lb + ad);
    const vh2 b2 = __builtin_bit_cast(vh2, in ? bb : 0u);
    a.h2[0] += b2 * xv.h2[0];
    a.h2[1] += b2 * xv.h2[1];
    a.h2[2] += b2 * xv.h2[2];
    a.h2[3] += b2 * xv.h2[3];
}

// 4 segment passes over a [ROWS][BATCH] fp16 table staged through LDS.
static __device__ __forceinline__ void pass4(
    const RowRegs& R, const _Float16* __restrict__ src,
    _Float16* lds, int tid, int soffb, V8 acc[4])
{
    const char* lb = (const char*)lds;
    #pragma unroll 1
    for (int p = 0; p < NSEG; ++p) {
        __syncthreads();   // previous segment fully consumed before overwrite
        const char* gseg = (const char*)(src + (size_t)p * SEGR * BATCH);
        #pragma unroll
        for (int tch = 0; tch < 16; ++tch) {
            const int off = tch * 8192 + tid * 16;
            __builtin_amdgcn_global_load_lds(
                (const __attribute__((address_space(1))) unsigned int*)(gseg + off),
                (__attribute__((address_space(3))) unsigned int*)((char*)lds + off),
                16, 0, 0);
        }
        __syncthreads();   // compiler drains vmcnt before s_barrier

        #pragma unroll
        for (int t = 0; t < 4; ++t) {
            #pragma unroll
            for (int u = 0; u < 4; ++u) {
                proc1(R.iv[t][u].x, R.hh[t][4*u+0], p, lb, soffb, acc[t]);
                proc1(R.iv[t][u].y, R.hh[t][4*u+1], p, lb, soffb, acc[t]);
                proc1(R.iv[t][u].z, R.hh[t][4*u+2], p, lb, soffb, acc[t]);
                proc1(R.iv[t][u].w, R.hh[t][4*u+3], p, lb, soffb, acc[t]);
            }
        }
    }
}

// Manual grid barrier: monotone counter in ws (zeroed by bar_init dispatch).
// tid0: one release fence -> RELAXED arrive -> RELAXED poll -> one acquire
// fence. No per-poll cache maintenance (the R13 bug). All 256 blocks are
// co-resident by construction (1 block/CU, 256 CUs).
static __device__ __forceinline__ void gridbar(unsigned* bar, unsigned target)
{
    __syncthreads();                       // all block stores complete
    if (threadIdx.x == 0) {
        __threadfence();                   // release: flush dirty L2 (once)
        __hip_atomic_fetch_add(bar, 1u, __ATOMIC_RELAXED,
                               __HIP_MEMORY_SCOPE_AGENT);
        while (__hip_atomic_load(bar, __ATOMIC_RELAXED,
                                 __HIP_MEMORY_SCOPE_AGENT) < target) {
            __builtin_amdgcn_s_sleep(8);
        }
        __threadfence();                   // acquire: invalidate stale (once)
    }
    __syncthreads();
}

__global__ void bar_init(unsigned* bar)
{
    if (threadIdx.x == 0)
        __hip_atomic_store(bar, 0u, __ATOMIC_RELEASE, __HIP_MEMORY_SCOPE_AGENT);
}

__global__ __launch_bounds__(THREADS, 2) void fused_spmv(
    const float* __restrict__ x,       // [ROWS, BATCH] fp32
    const int*   __restrict__ a_idx,   // [ROWS, NNZ]
    const float* __restrict__ a_vals,  // [ROWS, NNZ]
    const int*   __restrict__ b_idx,   // [ROWS, NNZ]
    const float* __restrict__ b_vals,  // [ROWS, NNZ]
    _Float16*    __restrict__ x16,     // ws: [ROWS, BATCH] fp16
    _Float16*    __restrict__ bx16,    // ws: [ROWS, BATCH] fp16
    float*       __restrict__ out,     // [BATCH, ROWS] fp32
    unsigned*    __restrict__ bar)     // ws: grid barrier counter
{
    __shared__ __attribute__((aligned(16))) _Float16 lds[SEGR * BATCH]; // 128KB

    const int tid   = threadIdx.x;
    const int wave  = tid >> 6;          // 0..7
    const int lane  = tid & 63;
    const int s     = lane & 3;          // batch octet id
    const int q     = lane >> 2;         // nnz block of 16
    const int soffb = s * 16;            // byte offset within a 64B table row
    const int rbase = blockIdx.x * RPB;
    const int r0    = rbase + wave * 4;  // this wave's first row

    // ---- Phase A: b-rows prologue (cold HBM, issue first) + x convert ----
    RowRegs RB;
    load_rows(b_idx, b_vals, r0, q, RB);
    {
        const int gid = blockIdx.x * THREADS + tid;     // 2 f32 per thread
        const float2 v = ((const float2*)x)[gid];
        vh2 h; h.x = (_Float16)v.x; h.y = (_Float16)v.y;
        ((vh2*)x16)[gid] = h;
    }
    gridbar(bar, BLOCKS);                // x16 fully written, device-visible

    // ---- Phase B: bx = B @ x16 ----
    V8 acc[4];
    #pragma unroll
    for (int t = 0; t < 4; ++t) {
        acc[t].u[0] = 0; acc[t].u[1] = 0; acc[t].u[2] = 0; acc[t].u[3] = 0;
    }
    pass4(RB, x16, lds, tid, soffb, acc);

    // a-rows prologue NOW: latency hides under B-epilogue + barrier + C
    // staging; registers survive the grid barrier -> phase C needs zero
    // idx/vals memory traffic.
    RowRegs RA;
    load_rows(a_idx, a_vals, r0, q, RA);

    // B epilogue: widen, reduce across 16 q-blocks, write bx16 rows
    #pragma unroll
    for (int t = 0; t < 4; ++t) {
        float a32[8];
        #pragma unroll
        for (int j = 0; j < 8; ++j) a32[j] = (float)acc[t].h8[j];
        #pragma unroll
        for (int d = 4; d < 64; d <<= 1) {
            #pragma unroll
            for (int j = 0; j < 8; ++j) a32[j] += __shfl_xor(a32[j], d);
        }
        if (q == 0) {                    // lanes 0..3: 64B coalesced
            vh8 h;
            #pragma unroll
            for (int j = 0; j < 8; ++j) h[j] = (_Float16)a32[j];
            *(vh8*)(bx16 + (size_t)(r0 + t) * BATCH + s * 8) = h;
        }
    }
    gridbar(bar, 2 * BLOCKS);            // bx16 fully written, device-visible

    // ---- Phase C: out = A @ bx16 ----
    #pragma unroll
    for (int t = 0; t < 4; ++t) {
        acc[t].u[0] = 0; acc[t].u[1] = 0; acc[t].u[2] = 0; acc[t].u[3] = 0;
    }
    pass4(RA, bx16, lds, tid, soffb, acc);

    __syncthreads();                     // table reads done; reuse lds as tile
    float* tile = (float*)lds;           // [32][33] padded
    #pragma unroll
    for (int t = 0; t < 4; ++t) {
        float a32[8];
        #pragma unroll
        for (int j = 0; j < 8; ++j) a32[j] = (float)acc[t].h8[j];
        #pragma unroll
        for (int d = 4; d < 64; d <<= 1) {
            #pragma unroll
            for (int j = 0; j < 8; ++j) a32[j] += __shfl_xor(a32[j], d);
        }
        if (q == 0) {
            const int rl = wave * 4 + t;
            #pragma unroll
            for (int j = 0; j < 8; ++j) tile[rl * 33 + s * 8 + j] = a32[j];
        }
    }
    __syncthreads();
    // out[b*ROWS + rbase + rr]: each thread stores 2 consecutive rows
    {
        const int e  = tid * 2;          // 1024 elems total
        const int b  = e >> 5;           // 0..31
        const int rr = e & 31;           // even
        float2 v2;
        v2.x = tile[rr * 33 + b];
        v2.y = tile[(rr + 1) * 33 + b];
        *(float2*)(out + (size_t)b * ROWS + rbase + rr) = v2;
    }
}

extern "C" void kernel_launch(void* const* d_in, const int* in_sizes, int n_in,
                              void* d_out, int out_size, void* d_ws, size_t ws_size,
                              hipStream_t stream) {
    (void)in_sizes; (void)n_in; (void)out_size; (void)ws_size;
    // setup_inputs order: x, a_idx, a_vals, b_idx, b_vals
    const float* x      = (const float*)d_in[0];   // [N, BATCH]
    const int*   a_idx  = (const int*)  d_in[1];   // [M, NNZ]
    const float* a_vals = (const float*)d_in[2];   // [M, NNZ]
    const int*   b_idx  = (const int*)  d_in[3];   // [K, NNZ]
    const float* b_vals = (const float*)d_in[4];   // [K, NNZ]
    float*       out    = (float*)d_out;           // [BATCH, M] fp32

    _Float16* bx16 = (_Float16*)d_ws;                         // 512 KB
    _Float16* x16  = bx16 + (size_t)ROWS * BATCH;             // 512 KB
    unsigned* bar  = (unsigned*)((char*)d_ws +
                                 (size_t)2 * ROWS * BATCH * sizeof(_Float16));

    bar_init<<<dim3(1), dim3(64), 0, stream>>>(bar);
    fused_spmv<<<dim3(BLOCKS), dim3(THREADS), 0, stream>>>(
        x, a_idx, a_vals, b_idx, b_vals, x16, bx16, out, bar);
}

// Round 5
// 145.236 us; speedup vs baseline: 1.7480x; 1.1569x over previous
//
#include <hip/hip_runtime.h>

// Double-sparse matvec: y = A @ (B @ x), ELL form.
// M=N=K=8192, NNZ=256 per row, BATCH=32, fp32 in/out.
//
// R15 = R14 (fused, relaxed-poll barrier) + ONE mechanism change: eliminate
// ALL cache-maintenance from the barriers. R14 still stalled ~65us (VALUBusy
// 17% => compute intact, 2 warm passes ~18us of VALU): each of the 32
// blocks/XCD issued its own __threadfence (buffer_wbl2/buffer_inv = full L2
// tag-walk, serialized at the XCD's L2) twice per barrier. Fix: the only
// cross-barrier data (x16, bx16 -- 2KB/block each) is now written with
// RELAXED AGENT-scope atomic stores (global_store sc1, write-through to the
// L3 coherence point). Release needs only vmcnt(0) (__syncthreads provides
// it); acquire needs nothing (no reader L2 can hold a STALE x16/bx16 line:
// L2s start empty for ws after the previous dispatch boundary, and these
// addresses are only L2-allocated by loads after the producing barrier).
// Barrier = syncthreads -> relaxed arrive -> relaxed poll -> syncthreads.
//
// Grid: 256 blocks x 512 threads, 128KB LDS -> exactly 1 block/CU on 256
// CUs -> co-residency guaranteed; monotone barrier targets 256 then 512.
//
// Lane layout (per row): lane = q*4 + s.
//   s in [0,4): batch octet -- 8 fp16 batch columns (16B) per lane
//   q in [0,16): owns nnz block j = q*16 .. q*16+15

#define NNZ     256
#define BATCH   32
#define ROWS    8192
#define SEGR    2048          // table rows per LDS segment
#define NSEG    4
#define RPB     32            // rows per block
#define THREADS 512
#define BLOCKS  (ROWS / RPB)  // 256

typedef int      vi4 __attribute__((ext_vector_type(4)));
typedef float    vf4 __attribute__((ext_vector_type(4)));
typedef _Float16 vh2 __attribute__((ext_vector_type(2)));
typedef _Float16 vh8 __attribute__((ext_vector_type(8)));

union V8 { vh8 h8; vh2 h2[4]; unsigned u[4]; };

struct RowRegs { vi4 iv[4][4]; unsigned hh[4][16]; };

// fp32 -> fp16 broadcast-pair (both halves of a u32 hold the same fp16)
static __device__ __forceinline__ unsigned hpack(float f)
{
    const unsigned short u = __builtin_bit_cast(unsigned short, (_Float16)f);
    return ((unsigned)u << 16) | (unsigned)u;
}

// Load 4 rows' worth of idx/vals (this lane's q-block) into registers.
static __device__ __forceinline__ void load_rows(
    const int* __restrict__ idx, const float* __restrict__ vals,
    int r0, int q, RowRegs& R)
{
    #pragma unroll
    for (int t = 0; t < 4; ++t) {
        const vi4* i4 = (const vi4*)(idx  + (size_t)(r0 + t) * NNZ) + q * 4;
        const vf4* v4 = (const vf4*)(vals + (size_t)(r0 + t) * NNZ) + q * 4;
        vf4 vv[4];
        #pragma unroll
        for (int u = 0; u < 4; ++u) R.iv[t][u] = __builtin_nontemporal_load(i4 + u);
        #pragma unroll
        for (int u = 0; u < 4; ++u) vv[u]      = __builtin_nontemporal_load(v4 + u);
        #pragma unroll
        for (int u = 0; u < 4; ++u) {
            R.hh[t][4*u+0] = hpack(vv[u].x);
            R.hh[t][4*u+1] = hpack(vv[u].y);
            R.hh[t][4*u+2] = hpack(vv[u].z);
            R.hh[t][4*u+3] = hpack(vv[u].w);
        }
    }
}

// One nnz, branchless segment-membership:
//  in-segment : gather the row's 16B slice for this s, pk_fma with bcast val
//  out-of-seg : uniform addr soffb (LDS broadcast, conflict-free), fma by 0.
static __device__ __forceinline__ void proc1(
    int k, unsigned bb, int p, const char* lb, int soffb, V8& a)
{
    const bool in = (((unsigned)k >> 11) == (unsigned)p);
    const int  ra = ((k & 2047) << 6) + soffb;
    const int  ad = in ? ra : soffb;
    V8 xv;
    xv.h8 = *(const vh8*)(lb + ad);
    const vh2 b2 = __builtin_bit_cast(vh2, in ? bb : 0u);
    a.h2[0] += b2 * xv.h2[0];
    a.h2[1] += b2 * xv.h2[1];
    a.h2[2] += b2 * xv.h2[2];
    a.h2[3] += b2 * xv.h2[3];
}

// 4 segment passes over a [ROWS][BATCH] fp16 table staged through LDS.
static __device__ __forceinline__ void pass4(
    const RowRegs& R, const _Float16* __restrict__ src,
    _Float16* lds, int tid, int soffb, V8 acc[4])
{
    const char* lb = (const char*)lds;
    #pragma unroll 1
    for (int p = 0; p < NSEG; ++p) {
        __syncthreads();   // previous segment fully consumed before overwrite
        const char* gseg = (const char*)(src + (size_t)p * SEGR * BATCH);
        #pragma unroll
        for (int tch = 0; tch < 16; ++tch) {
            const int off = tch * 8192 + tid * 16;
            __builtin_amdgcn_global_load_lds(
                (const __attribute__((address_space(1))) unsigned int*)(gseg + off),
                (__attribute__((address_space(3))) unsigned int*)((char*)lds + off),
                16, 0, 0);
        }
        __syncthreads();   // compiler drains vmcnt before s_barrier

        #pragma unroll
        for (int t = 0; t < 4; ++t) {
            #pragma unroll
            for (int u = 0; u < 4; ++u) {
                proc1(R.iv[t][u].x, R.hh[t][4*u+0], p, lb, soffb, acc[t]);
                proc1(R.iv[t][u].y, R.hh[t][4*u+1], p, lb, soffb, acc[t]);
                proc1(R.iv[t][u].z, R.hh[t][4*u+2], p, lb, soffb, acc[t]);
                proc1(R.iv[t][u].w, R.hh[t][4*u+3], p, lb, soffb, acc[t]);
            }
        }
    }
}

// Manual grid barrier: monotone counter in ws (zeroed by bar_init dispatch).
// NO cache maintenance: cross-barrier data is written with sc1 write-through
// stores (already at the coherence point when vmcnt drains in __syncthreads),
// and no reader L2 can hold stale copies (see header comment).
// All 256 blocks are co-resident by construction (1 block/CU, 256 CUs).
static __device__ __forceinline__ void gridbar(unsigned* bar, unsigned target)
{
    __syncthreads();                       // all block stores complete (vmcnt 0)
    if (threadIdx.x == 0) {
        __hip_atomic_fetch_add(bar, 1u, __ATOMIC_RELAXED,
                               __HIP_MEMORY_SCOPE_AGENT);
        while (__hip_atomic_load(bar, __ATOMIC_RELAXED,
                                 __HIP_MEMORY_SCOPE_AGENT) < target) {
            __builtin_amdgcn_s_sleep(16);
        }
    }
    __syncthreads();
}

// Write-through agent-scope store of one dword (global_store sc1: visible at
// the device coherence point once vmcnt drains; no L2 dirty state).
static __device__ __forceinline__ void st_agent_u32(unsigned* p, unsigned v)
{
    __hip_atomic_store(p, v, __ATOMIC_RELAXED, __HIP_MEMORY_SCOPE_AGENT);
}

__global__ void bar_init(unsigned* bar)
{
    if (threadIdx.x == 0)
        __hip_atomic_store(bar, 0u, __ATOMIC_RELEASE, __HIP_MEMORY_SCOPE_AGENT);
}

__global__ __launch_bounds__(THREADS, 2) void fused_spmv(
    const float* __restrict__ x,       // [ROWS, BATCH] fp32
    const int*   __restrict__ a_idx,   // [ROWS, NNZ]
    const float* __restrict__ a_vals,  // [ROWS, NNZ]
    const int*   __restrict__ b_idx,   // [ROWS, NNZ]
    const float* __restrict__ b_vals,  // [ROWS, NNZ]
    _Float16*    __restrict__ x16,     // ws: [ROWS, BATCH] fp16
    _Float16*    __restrict__ bx16,    // ws: [ROWS, BATCH] fp16
    float*       __restrict__ out,     // [BATCH, ROWS] fp32
    unsigned*    __restrict__ bar)     // ws: grid barrier counter
{
    __shared__ __attribute__((aligned(16))) _Float16 lds[SEGR * BATCH]; // 128KB

    const int tid   = threadIdx.x;
    const int wave  = tid >> 6;          // 0..7
    const int lane  = tid & 63;
    const int s     = lane & 3;          // batch octet id
    const int q     = lane >> 2;         // nnz block of 16
    const int soffb = s * 16;            // byte offset within a 64B table row
    const int rbase = blockIdx.x * RPB;
    const int r0    = rbase + wave * 4;  // this wave's first row

    // ---- Phase A: b-rows prologue (cold HBM, issue first) + x convert ----
    RowRegs RB;
    load_rows(b_idx, b_vals, r0, q, RB);
    {
        const int gid = blockIdx.x * THREADS + tid;     // 2 f32 per thread
        const float2 v = ((const float2*)x)[gid];
        vh2 h; h.x = (_Float16)v.x; h.y = (_Float16)v.y;
        st_agent_u32((unsigned*)x16 + gid, __builtin_bit_cast(unsigned, h));
    }
    gridbar(bar, BLOCKS);                // x16 fully written, device-visible

    // ---- Phase B: bx = B @ x16 ----
    V8 acc[4];
    #pragma unroll
    for (int t = 0; t < 4; ++t) {
        acc[t].u[0] = 0; acc[t].u[1] = 0; acc[t].u[2] = 0; acc[t].u[3] = 0;
    }
    pass4(RB, x16, lds, tid, soffb, acc);

    // a-rows prologue NOW: latency hides under B-epilogue + barrier + C
    // staging; registers survive the grid barrier -> phase C needs zero
    // idx/vals memory traffic.
    RowRegs RA;
    load_rows(a_idx, a_vals, r0, q, RA);

    // B epilogue: widen, reduce across 16 q-blocks, write bx16 rows
    #pragma unroll
    for (int t = 0; t < 4; ++t) {
        float a32[8];
        #pragma unroll
        for (int j = 0; j < 8; ++j) a32[j] = (float)acc[t].h8[j];
        #pragma unroll
        for (int d = 4; d < 64; d <<= 1) {
            #pragma unroll
            for (int j = 0; j < 8; ++j) a32[j] += __shfl_xor(a32[j], d);
        }
        if (q == 0) {                    // lanes 0..3: 16B each, sc1 stores
            V8 cv;
            #pragma unroll
            for (int j = 0; j < 8; ++j) cv.h8[j] = (_Float16)a32[j];
            unsigned* dp = (unsigned*)(bx16 + (size_t)(r0 + t) * BATCH + s * 8);
            #pragma unroll
            for (int w = 0; w < 4; ++w) st_agent_u32(dp + w, cv.u[w]);
        }
    }
    gridbar(bar, 2 * BLOCKS);            // bx16 fully written, device-visible

    // ---- Phase C: out = A @ bx16 ----
    #pragma unroll
    for (int t = 0; t < 4; ++t) {
        acc[t].u[0] = 0; acc[t].u[1] = 0; acc[t].u[2] = 0; acc[t].u[3] = 0;
    }
    pass4(RA, bx16, lds, tid, soffb, acc);

    __syncthreads();                     // table reads done; reuse lds as tile
    float* tile = (float*)lds;           // [32][33] padded
    #pragma unroll
    for (int t = 0; t < 4; ++t) {
        float a32[8];
        #pragma unroll
        for (int j = 0; j < 8; ++j) a32[j] = (float)acc[t].h8[j];
        #pragma unroll
        for (int d = 4; d < 64; d <<= 1) {
            #pragma unroll
            for (int j = 0; j < 8; ++j) a32[j] += __shfl_xor(a32[j], d);
        }
        if (q == 0) {
            const int rl = wave * 4 + t;
            #pragma unroll
            for (int j = 0; j < 8; ++j) tile[rl * 33 + s * 8 + j] = a32[j];
        }
    }
    __syncthreads();
    // out[b*ROWS + rbase + rr]: each thread stores 2 consecutive rows
    {
        const int e  = tid * 2;          // 1024 elems total
        const int b  = e >> 5;           // 0..31
        const int rr = e & 31;           // even
        float2 v2;
        v2.x = tile[rr * 33 + b];
        v2.y = tile[(rr + 1) * 33 + b];
        *(float2*)(out + (size_t)b * ROWS + rbase + rr) = v2;
    }
}

extern "C" void kernel_launch(void* const* d_in, const int* in_sizes, int n_in,
                              void* d_out, int out_size, void* d_ws, size_t ws_size,
                              hipStream_t stream) {
    (void)in_sizes; (void)n_in; (void)out_size; (void)ws_size;
    // setup_inputs order: x, a_idx, a_vals, b_idx, b_vals
    const float* x      = (const float*)d_in[0];   // [N, BATCH]
    const int*   a_idx  = (const int*)  d_in[1];   // [M, NNZ]
    const float* a_vals = (const float*)d_in[2];   // [M, NNZ]
    const int*   b_idx  = (const int*)  d_in[3];   // [K, NNZ]
    const float* b_vals = (const float*)d_in[4];   // [K, NNZ]
    float*       out    = (float*)d_out;           // [BATCH, M] fp32

    _Float16* bx16 = (_Float16*)d_ws;                         // 512 KB
    _Float16* x16  = bx16 + (size_t)ROWS * BATCH;             // 512 KB
    unsigned* bar  = (unsigned*)((char*)d_ws +
                                 (size_t)2 * ROWS * BATCH * sizeof(_Float16));

    bar_init<<<dim3(1), dim3(64), 0, stream>>>(bar);
    fused_spmv<<<dim3(BLOCKS), dim3(THREADS), 0, stream>>>(
        x, a_idx, a_vals, b_idx, b_vals, x16, bx16, out, bar);
}